// Round 1
// baseline (174.630 us; speedup 1.0000x reference)
//
#include <hip/hip_runtime.h>
#include <hip/hip_bf16.h>
#include <stdint.h>
#include <stddef.h>

#define TT 4096
#define CC 1024
#define NFD 1024
#define N3 3072

typedef __bf16 bf16;
typedef __bf16 bf16x8 __attribute__((ext_vector_type(8)));
typedef __bf16 bf16x4 __attribute__((ext_vector_type(4)));
typedef float f32x4 __attribute__((ext_vector_type(4)));

typedef const __attribute__((address_space(1))) unsigned char gl_u8;
typedef __attribute__((address_space(3))) unsigned char lds_u8;

__device__ __forceinline__ void glds16(const void* g, void* l) {
  __builtin_amdgcn_global_load_lds((gl_u8*)g, (lds_u8*)l, 16, 0, 0);
}

// Stage a 128x32 bf16 tile (row-major, ld in elements) into linear LDS [128][32].
// global_load_lds: dest = wave-uniform base + lane*16 (m104/m108), so LDS stays linear.
__device__ __forceinline__ void stage128x32(const bf16* __restrict__ src, int ld, bf16* lds, int tid) {
  const int lane = tid & 63;
  const int w = tid >> 6;
#pragma unroll
  for (int p = 0; p < 2; ++p) {
    const int lbyte = w * 2048 + p * 1024;              // wave-uniform LDS base (bytes)
    const int row = (lbyte >> 6) + (lane >> 2);         // this lane's 16B lands at row, k8
    const int kel = (lane & 3) << 3;
    glds16(src + row * ld + kel, (char*)lds + lbyte);
  }
}

// 128x128 output tile, 4 waves (2x2 of 64x64), BK=32, NT layout (both tiles [128][32]).
__device__ __forceinline__ void gemm_core(const bf16* __restrict__ A, const bf16* __restrict__ B,
                                          int lda, int ldb, int ksteps,
                                          bf16* As, bf16* Bs, int tid, f32x4 (&acc)[4][4]) {
  const int lane = tid & 63;
  const int w = tid >> 6;
  const int wm = (w >> 1) * 64;
  const int wn = (w & 1) * 64;
  const int lrow = lane & 15;
  const int lko = (lane >> 4) * 8;
  for (int ks = 0; ks < ksteps; ++ks) {
    stage128x32(A + ks * 32, lda, As, tid);
    stage128x32(B + ks * 32, ldb, Bs, tid);
    __syncthreads();
    bf16x8 af[4], bfr[4];
#pragma unroll
    for (int i = 0; i < 4; ++i)
      af[i] = *(const bf16x8*)(As + (wm + i * 16 + lrow) * 32 + lko);
#pragma unroll
    for (int i = 0; i < 4; ++i)
      bfr[i] = *(const bf16x8*)(Bs + (wn + i * 16 + lrow) * 32 + lko);
#pragma unroll
    for (int mi = 0; mi < 4; ++mi)
#pragma unroll
      for (int ni = 0; ni < 4; ++ni)
        acc[mi][ni] = __builtin_amdgcn_mfma_f32_16x16x32_bf16(af[mi], bfr[ni], acc[mi][ni], 0, 0, 0);
    __syncthreads();
  }
}

// ---- K0a: fp32 -> bf16 straight conversion (x) ----
__global__ void k_cvt(const float* __restrict__ src, bf16* __restrict__ dst, int n) {
  int idx = (blockIdx.x * blockDim.x + threadIdx.x) * 8;
  if (idx >= n) return;
  f32x4 a = *(const f32x4*)(src + idx);
  f32x4 b = *(const f32x4*)(src + idx + 4);
  bf16x8 o;
#pragma unroll
  for (int j = 0; j < 4; ++j) { o[j] = (bf16)a[j]; o[4 + j] = (bf16)b[j]; }
  *(bf16x8*)(dst + idx) = o;
}

// ---- K0b: W [C][3N] fp32 -> WbT [3N][C] bf16 (tiled transpose via LDS) ----
__global__ __launch_bounds__(256) void k_wT(const float* __restrict__ Wsrc, bf16* __restrict__ WbT) {
  __shared__ float Ls[64][68];
  const int n0 = blockIdx.x * 64;
  const int c0 = blockIdx.y * 64;
  const int tid = threadIdx.x;
#pragma unroll
  for (int qq = 0; qq < 4; ++qq) {
    int lin = qq * 1024 + tid * 4;
    int r = lin >> 6, cc = lin & 63;
    f32x4 v = *(const f32x4*)(Wsrc + (size_t)(c0 + r) * N3 + n0 + cc);
#pragma unroll
    for (int j = 0; j < 4; ++j) Ls[r][cc + j] = v[j];
  }
  __syncthreads();
#pragma unroll
  for (int qq = 0; qq < 4; ++qq) {
    int lin = qq * 1024 + tid * 4;
    int nr = lin >> 6, cc = lin & 63;
    bf16x4 o;
#pragma unroll
    for (int j = 0; j < 4; ++j) o[j] = (bf16)Ls[cc + j][nr];
    *(bf16x4*)(WbT + (size_t)(n0 + nr) * CC + c0 + cc) = o;
  }
}

// ---- K1: qkv = xb @ WbT^T + b ; writes q,k natural [t][c] and v transposed [d][t] ----
__global__ __launch_bounds__(256, 2) void k_qkv(const bf16* __restrict__ xb, const bf16* __restrict__ wbt,
                                                const float* __restrict__ bias,
                                                bf16* __restrict__ q, bf16* __restrict__ k,
                                                bf16* __restrict__ vT) {
  __shared__ bf16 As[128 * 32], Bs[128 * 32];
  const int tid = threadIdx.x;
  const int m0 = blockIdx.y * 128;
  const int n0 = blockIdx.x * 128;
  f32x4 acc[4][4];
#pragma unroll
  for (int i = 0; i < 4; ++i)
#pragma unroll
    for (int j = 0; j < 4; ++j) acc[i][j] = (f32x4){0.f, 0.f, 0.f, 0.f};

  gemm_core(xb + (size_t)m0 * CC, wbt + (size_t)n0 * CC, CC, CC, CC / 32, As, Bs, tid, acc);

  const int lane = tid & 63;
  const int w = tid >> 6;
  const int wm = (w >> 1) * 64, wn = (w & 1) * 64;
  const int seg = n0 >> 10;  // 0:q 1:k 2:v  (block's 128-col range never straddles)
#pragma unroll
  for (int mi = 0; mi < 4; ++mi) {
    const int tB = m0 + wm + mi * 16 + ((lane >> 4) << 2);
#pragma unroll
    for (int ni = 0; ni < 4; ++ni) {
      const int n = n0 + wn + ni * 16 + (lane & 15);
      const float bb = bias[n];
      f32x4 a = acc[mi][ni];
      if (seg == 2) {
        bf16x4 pv;
#pragma unroll
        for (int r = 0; r < 4; ++r) pv[r] = (bf16)(a[r] + bb);
        *(bf16x4*)(vT + (size_t)(n - 2048) * TT + tB) = pv;  // vT[d][t], 8B store
      } else {
        bf16* dst = (seg == 0) ? q : k;
        const int nl = n & 1023;
#pragma unroll
        for (int r = 0; r < 4; ++r) dst[(size_t)(tB + r) * NFD + nl] = (bf16)(a[r] + bb);
      }
    }
  }
}

// ---- K2: P' = exp(mask(q @ k^T / 32)) as bf16; row sums l via atomicAdd ----
__global__ __launch_bounds__(256, 2) void k_scores(const bf16* __restrict__ q, const bf16* __restrict__ kk,
                                                   bf16* __restrict__ P, float* __restrict__ l,
                                                   const int* __restrict__ npadd_p) {
  const int jt = blockIdx.x, it = blockIdx.y;
  const int np = *npadd_p;
  const int jt0 = np >> 7;
  if (jt > it || jt < jt0) return;  // fully-masked tile: never read by K3
  __shared__ bf16 As[128 * 32], Bs[128 * 32];
  const int tid = threadIdx.x;
  f32x4 acc[4][4];
#pragma unroll
  for (int i = 0; i < 4; ++i)
#pragma unroll
    for (int j = 0; j < 4; ++j) acc[i][j] = (f32x4){0.f, 0.f, 0.f, 0.f};

  gemm_core(q + (size_t)it * 128 * CC, kk + (size_t)jt * 128 * CC, CC, CC, CC / 32, As, Bs, tid, acc);

  const int lane = tid & 63;
  const int w = tid >> 6;
  const int wm = (w >> 1) * 64, wn = (w & 1) * 64;
  const float scale = 0.03125f;  // 1/sqrt(1024)
#pragma unroll
  for (int mi = 0; mi < 4; ++mi) {
    const int iB = it * 128 + wm + mi * 16 + ((lane >> 4) << 2);
    float rs[4] = {0.f, 0.f, 0.f, 0.f};
#pragma unroll
    for (int ni = 0; ni < 4; ++ni) {
      const int j = jt * 128 + wn + ni * 16 + (lane & 15);
      f32x4 a = acc[mi][ni];
#pragma unroll
      for (int r = 0; r < 4; ++r) {
        const int i = iB + r;
        float p = 0.f;
        if (j <= i && j >= np && i >= np) p = __expf(a[r] * scale);
        const bf16 pb = (bf16)p;
        P[(size_t)i * TT + j] = pb;
        rs[r] += (float)pb;  // sum the rounded value: weights then sum to exactly l
      }
    }
#pragma unroll
    for (int r = 0; r < 4; ++r) {
      float v = rs[r];
      v += __shfl_xor(v, 1);
      v += __shfl_xor(v, 2);
      v += __shfl_xor(v, 4);
      v += __shfl_xor(v, 8);
      if ((lane & 15) == 0) atomicAdd(&l[iB + r], v);
    }
  }
}

// ---- K3: y = (P' @ v) / l, zero for padded rows ----
__global__ __launch_bounds__(256, 2) void k_pv(const bf16* __restrict__ P, const bf16* __restrict__ vT,
                                               const float* __restrict__ l, float* __restrict__ y,
                                               const int* __restrict__ npadd_p) {
  const int d0 = blockIdx.x * 128;
  const int it = blockIdx.y;
  const int np = *npadd_p;
  const int jt0 = np >> 7;
  __shared__ bf16 As[128 * 32], Bs[128 * 32];
  const int tid = threadIdx.x;
  f32x4 acc[4][4];
#pragma unroll
  for (int i = 0; i < 4; ++i)
#pragma unroll
    for (int j = 0; j < 4; ++j) acc[i][j] = (f32x4){0.f, 0.f, 0.f, 0.f};

  const int nkt = it - jt0 + 1;  // 128-wide j-tiles with any valid data
  if (nkt > 0) {
    gemm_core(P + (size_t)it * 128 * TT + (size_t)jt0 * 128,
              vT + (size_t)d0 * TT + (size_t)jt0 * 128,
              TT, TT, nkt * 4, As, Bs, tid, acc);
  }

  const int lane = tid & 63;
  const int w = tid >> 6;
  const int wm = (w >> 1) * 64, wn = (w & 1) * 64;
#pragma unroll
  for (int mi = 0; mi < 4; ++mi) {
    const int iB = it * 128 + wm + mi * 16 + ((lane >> 4) << 2);
#pragma unroll
    for (int ni = 0; ni < 4; ++ni) {
      const int d = d0 + wn + ni * 16 + (lane & 15);
      f32x4 a = acc[mi][ni];
#pragma unroll
      for (int r = 0; r < 4; ++r) {
        const int i = iB + r;
        float out = 0.f;
        if (i >= np) out = a[r] / l[i];
        y[(size_t)i * NFD + d] = out;
      }
    }
  }
}

extern "C" void kernel_launch(void* const* d_in, const int* in_sizes, int n_in,
                              void* d_out, int out_size, void* d_ws, size_t ws_size,
                              hipStream_t stream) {
  const float* x = (const float*)d_in[0];
  const float* W = (const float*)d_in[1];
  const float* b = (const float*)d_in[2];
  const int* npadd = (const int*)d_in[3];
  float* y = (float*)d_out;

  char* ws = (char*)d_ws;
  const size_t MB = 1u << 20;
  bf16* q  = (bf16*)(ws + 0 * MB);          // 8 MB  [T][C]
  bf16* kk = (bf16*)(ws + 8 * MB);          // 8 MB  [T][C]
  bf16* vT = (bf16*)(ws + 16 * MB);         // 8 MB  [D][T]
  float* l = (float*)(ws + 24 * MB);        // 16 KB
  bf16* P  = (bf16*)(ws + 24 * MB + 65536); // 32 MB [T][T]
  bf16* xb = P;                              // overlap: dead before K2 writes P
  bf16* WbT = (bf16*)((char*)P + 8 * MB);    // 6 MB, also dead before K2

  // K0: convert x, transpose+convert W
  k_cvt<<<dim3((TT * CC) / (256 * 8)), 256, 0, stream>>>(x, xb, TT * CC);
  k_wT<<<dim3(N3 / 64, CC / 64), 256, 0, stream>>>(W, WbT);
  // K1: QKV projection
  k_qkv<<<dim3(N3 / 128, TT / 128), 256, 0, stream>>>(xb, WbT, b, q, kk, vT);
  // K2: masked exp-scores + row sums
  hipMemsetAsync(l, 0, TT * sizeof(float), stream);
  k_scores<<<dim3(TT / 128, TT / 128), 256, 0, stream>>>(q, kk, P, l, npadd);
  // K3: PV + normalize
  k_pv<<<dim3(NFD / 128, TT / 128), 256, 0, stream>>>(P, vT, l, y, npadd);
}

// Round 2
// 151.393 us; speedup vs baseline: 1.1535x; 1.1535x over previous
//
#include <hip/hip_runtime.h>
#include <hip/hip_bf16.h>
#include <stdint.h>
#include <stddef.h>

#define TT 4096
#define CC 1024
#define NFD 1024
#define N3 3072

typedef __bf16 bf16;
typedef __bf16 bf16x8 __attribute__((ext_vector_type(8)));
typedef __bf16 bf16x4 __attribute__((ext_vector_type(4)));
typedef float f32x4 __attribute__((ext_vector_type(4)));

typedef const __attribute__((address_space(1))) unsigned char gl_u8;
typedef __attribute__((address_space(3))) unsigned char lds_u8;

__device__ __forceinline__ void glds16(const void* g, void* l) {
  __builtin_amdgcn_global_load_lds((gl_u8*)g, (lds_u8*)l, 16, 0, 0);
}

// Stage a 128x32 bf16 tile (row-major, ld in elements) into linear LDS [128][32].
__device__ __forceinline__ void stage128x32(const bf16* __restrict__ src, int ld, bf16* lds, int tid) {
  const int lane = tid & 63;
  const int w = tid >> 6;
#pragma unroll
  for (int p = 0; p < 2; ++p) {
    const int lbyte = w * 2048 + p * 1024;              // wave-uniform LDS base (bytes)
    const int row = (lbyte >> 6) + (lane >> 2);         // this lane's 16B lands at row, k8
    const int kel = (lane & 3) << 3;
    glds16(src + row * ld + kel, (char*)lds + lbyte);
  }
}

// 128x128 output tile, 4 waves (2x2 of 64x64), BK=32, NT layout (both tiles [128][32]).
__device__ __forceinline__ void gemm_core(const bf16* __restrict__ A, const bf16* __restrict__ B,
                                          int lda, int ldb, int ksteps,
                                          bf16* As, bf16* Bs, int tid, f32x4 (&acc)[4][4]) {
  const int lane = tid & 63;
  const int w = tid >> 6;
  const int wm = (w >> 1) * 64;
  const int wn = (w & 1) * 64;
  const int lrow = lane & 15;
  const int lko = (lane >> 4) * 8;
  for (int ks = 0; ks < ksteps; ++ks) {
    stage128x32(A + ks * 32, lda, As, tid);
    stage128x32(B + ks * 32, ldb, Bs, tid);
    __syncthreads();
    bf16x8 af[4], bfr[4];
#pragma unroll
    for (int i = 0; i < 4; ++i)
      af[i] = *(const bf16x8*)(As + (wm + i * 16 + lrow) * 32 + lko);
#pragma unroll
    for (int i = 0; i < 4; ++i)
      bfr[i] = *(const bf16x8*)(Bs + (wn + i * 16 + lrow) * 32 + lko);
#pragma unroll
    for (int mi = 0; mi < 4; ++mi)
#pragma unroll
      for (int ni = 0; ni < 4; ++ni)
        acc[mi][ni] = __builtin_amdgcn_mfma_f32_16x16x32_bf16(af[mi], bfr[ni], acc[mi][ni], 0, 0, 0);
    __syncthreads();
  }
}

// ---- K0a: fp32 -> bf16 straight conversion (x) ----
__global__ void k_cvt(const float* __restrict__ src, bf16* __restrict__ dst, int n) {
  int idx = (blockIdx.x * blockDim.x + threadIdx.x) * 8;
  if (idx >= n) return;
  f32x4 a = *(const f32x4*)(src + idx);
  f32x4 b = *(const f32x4*)(src + idx + 4);
  bf16x8 o;
#pragma unroll
  for (int j = 0; j < 4; ++j) { o[j] = (bf16)a[j]; o[4 + j] = (bf16)b[j]; }
  *(bf16x8*)(dst + idx) = o;
}

// ---- K0b: W [C][3N] fp32 -> WbT [3N][C] bf16 (tiled transpose via LDS) ----
__global__ __launch_bounds__(256) void k_wT(const float* __restrict__ Wsrc, bf16* __restrict__ WbT) {
  __shared__ float Ls[64][68];
  const int n0 = blockIdx.x * 64;
  const int c0 = blockIdx.y * 64;
  const int tid = threadIdx.x;
#pragma unroll
  for (int qq = 0; qq < 4; ++qq) {
    int lin = qq * 1024 + tid * 4;
    int r = lin >> 6, cc = lin & 63;
    f32x4 v = *(const f32x4*)(Wsrc + (size_t)(c0 + r) * N3 + n0 + cc);
#pragma unroll
    for (int j = 0; j < 4; ++j) Ls[r][cc + j] = v[j];
  }
  __syncthreads();
#pragma unroll
  for (int qq = 0; qq < 4; ++qq) {
    int lin = qq * 1024 + tid * 4;
    int nr = lin >> 6, cc = lin & 63;
    bf16x4 o;
#pragma unroll
    for (int j = 0; j < 4; ++j) o[j] = (bf16)Ls[cc + j][nr];
    *(bf16x4*)(WbT + (size_t)(n0 + nr) * CC + c0 + cc) = o;
  }
}

// ---- K1: qkv = xb @ WbT^T + b ; writes q,k natural [t][c] and v transposed [d][t] ----
__global__ __launch_bounds__(256, 2) void k_qkv(const bf16* __restrict__ xb, const bf16* __restrict__ wbt,
                                                const float* __restrict__ bias,
                                                bf16* __restrict__ q, bf16* __restrict__ k,
                                                bf16* __restrict__ vT) {
  __shared__ bf16 As[128 * 32], Bs[128 * 32];
  const int tid = threadIdx.x;
  const int m0 = blockIdx.y * 128;
  const int n0 = blockIdx.x * 128;
  f32x4 acc[4][4];
#pragma unroll
  for (int i = 0; i < 4; ++i)
#pragma unroll
    for (int j = 0; j < 4; ++j) acc[i][j] = (f32x4){0.f, 0.f, 0.f, 0.f};

  gemm_core(xb + (size_t)m0 * CC, wbt + (size_t)n0 * CC, CC, CC, CC / 32, As, Bs, tid, acc);

  const int lane = tid & 63;
  const int w = tid >> 6;
  const int wm = (w >> 1) * 64, wn = (w & 1) * 64;
  const int seg = n0 >> 10;  // 0:q 1:k 2:v
#pragma unroll
  for (int mi = 0; mi < 4; ++mi) {
    const int tB = m0 + wm + mi * 16 + ((lane >> 4) << 2);
#pragma unroll
    for (int ni = 0; ni < 4; ++ni) {
      const int n = n0 + wn + ni * 16 + (lane & 15);
      const float bb = bias[n];
      f32x4 a = acc[mi][ni];
      if (seg == 2) {
        bf16x4 pv;
#pragma unroll
        for (int r = 0; r < 4; ++r) pv[r] = (bf16)(a[r] + bb);
        *(bf16x4*)(vT + (size_t)(n - 2048) * TT + tB) = pv;  // vT[d][t]
      } else {
        bf16* dst = (seg == 0) ? q : k;
        const int nl = n & 1023;
#pragma unroll
        for (int r = 0; r < 4; ++r) dst[(size_t)(tB + r) * NFD + nl] = (bf16)(a[r] + bb);
      }
    }
  }
}

// ---- K2: P' = exp(mask(q @ k^T / 32)) as bf16; row sums l via atomicAdd ----
__global__ __launch_bounds__(256, 2) void k_scores(const bf16* __restrict__ q, const bf16* __restrict__ kk,
                                                   bf16* __restrict__ P, float* __restrict__ l,
                                                   const int* __restrict__ npadd_p) {
  const int jt = blockIdx.x, it = blockIdx.y;
  const int np = *npadd_p;
  const int jt0 = np >> 7;
  if (jt > it || jt < jt0) return;  // fully-masked tile: never read by K3
  __shared__ bf16 As[128 * 32], Bs[128 * 32];
  const int tid = threadIdx.x;
  f32x4 acc[4][4];
#pragma unroll
  for (int i = 0; i < 4; ++i)
#pragma unroll
    for (int j = 0; j < 4; ++j) acc[i][j] = (f32x4){0.f, 0.f, 0.f, 0.f};

  gemm_core(q + (size_t)it * 128 * CC, kk + (size_t)jt * 128 * CC, CC, CC, CC / 32, As, Bs, tid, acc);

  const int lane = tid & 63;
  const int w = tid >> 6;
  const int wm = (w >> 1) * 64, wn = (w & 1) * 64;
  const float scale = 0.03125f;  // 1/sqrt(1024)
#pragma unroll
  for (int mi = 0; mi < 4; ++mi) {
    const int iB = it * 128 + wm + mi * 16 + ((lane >> 4) << 2);
    float rs[4] = {0.f, 0.f, 0.f, 0.f};
#pragma unroll
    for (int ni = 0; ni < 4; ++ni) {
      const int j = jt * 128 + wn + ni * 16 + (lane & 15);
      f32x4 a = acc[mi][ni];
#pragma unroll
      for (int r = 0; r < 4; ++r) {
        const int i = iB + r;
        float p = 0.f;
        if (j <= i && j >= np && i >= np) p = __expf(a[r] * scale);
        const bf16 pb = (bf16)p;
        P[(size_t)i * TT + j] = pb;
        rs[r] += (float)pb;  // sum the rounded value: weights then sum match exactly
      }
    }
#pragma unroll
    for (int r = 0; r < 4; ++r) {
      float v = rs[r];
      v += __shfl_xor(v, 1);
      v += __shfl_xor(v, 2);
      v += __shfl_xor(v, 4);
      v += __shfl_xor(v, 8);
      if ((lane & 15) == 0) atomicAdd(&l[iB + r], v);
    }
  }
}

// ---- K3a: split-K PV. chunk c covers j-tiles [8c, 8c+8); fp32 atomics into yacc ----
__global__ __launch_bounds__(256, 2) void k_pvc(const bf16* __restrict__ P, const bf16* __restrict__ vT,
                                                float* __restrict__ yacc,
                                                const int* __restrict__ npadd_p) {
  const int c = blockIdx.x;
  const int it = blockIdx.y;
  const int d0 = blockIdx.z * 128;
  const int np = *npadd_p;
  const int jt0 = np >> 7;
  int jlo = 8 * c; if (jlo < jt0) jlo = jt0;
  int jhi = 8 * c + 8; if (jhi > it + 1) jhi = it + 1;
  if (jlo >= jhi) return;  // empty / fully-masked chunk (also covers it < jt0)

  __shared__ bf16 As[128 * 32], Bs[128 * 32];
  const int tid = threadIdx.x;
  f32x4 acc[4][4];
#pragma unroll
  for (int i = 0; i < 4; ++i)
#pragma unroll
    for (int j = 0; j < 4; ++j) acc[i][j] = (f32x4){0.f, 0.f, 0.f, 0.f};

  gemm_core(P + (size_t)it * 128 * TT + (size_t)jlo * 128,
            vT + (size_t)d0 * TT + (size_t)jlo * 128,
            TT, TT, (jhi - jlo) * 4, As, Bs, tid, acc);

  const int lane = tid & 63;
  const int w = tid >> 6;
  const int wm = (w >> 1) * 64, wn = (w & 1) * 64;
  // sole-writer tile? (this chunk covers the row's entire valid j range)
  const bool full = (8 * c <= jt0) && (8 * c + 8 >= it + 1);
#pragma unroll
  for (int mi = 0; mi < 4; ++mi) {
    const int iB = it * 128 + wm + mi * 16 + ((lane >> 4) << 2);
#pragma unroll
    for (int ni = 0; ni < 4; ++ni) {
      const int d = d0 + wn + ni * 16 + (lane & 15);
      f32x4 a = acc[mi][ni];
#pragma unroll
      for (int r = 0; r < 4; ++r) {
        float* p = &yacc[(size_t)(iB + r) * NFD + d];
        if (full) *p = a[r];
        else atomicAdd(p, a[r]);
      }
    }
  }
}

// ---- K3b: y = yacc / l for i>=np else 0 ----
__global__ __launch_bounds__(256) void k_norm(const float* __restrict__ yacc, const float* __restrict__ l,
                                              float* __restrict__ y, const int* __restrict__ npadd_p) {
  const int idx = (blockIdx.x * 256 + threadIdx.x) * 4;
  const int i = idx >> 10;  // / NFD
  const int np = *npadd_p;
  f32x4 v = (f32x4){0.f, 0.f, 0.f, 0.f};
  if (i >= np) {
    f32x4 a = *(const f32x4*)(yacc + idx);
    const float inv = 1.0f / l[i];
#pragma unroll
    for (int j = 0; j < 4; ++j) v[j] = a[j] * inv;
  }
  *(f32x4*)(y + idx) = v;
}

extern "C" void kernel_launch(void* const* d_in, const int* in_sizes, int n_in,
                              void* d_out, int out_size, void* d_ws, size_t ws_size,
                              hipStream_t stream) {
  const float* x = (const float*)d_in[0];
  const float* W = (const float*)d_in[1];
  const float* b = (const float*)d_in[2];
  const int* npadd = (const int*)d_in[3];
  float* y = (float*)d_out;

  char* ws = (char*)d_ws;
  const size_t MB = 1u << 20;
  bf16* q  = (bf16*)(ws + 0 * MB);          // 8 MB  [T][C]   (dead after k_scores)
  bf16* kk = (bf16*)(ws + 8 * MB);          // 8 MB  [T][C]   (dead after k_scores)
  float* yacc = (float*)(ws + 0 * MB);      // 16 MB [T][D] fp32, overlays q+kk
  bf16* vT = (bf16*)(ws + 16 * MB);         // 8 MB  [D][T]
  float* l = (float*)(ws + 24 * MB);        // 16 KB
  bf16* P  = (bf16*)(ws + 24 * MB + 65536); // 32 MB [T][T]
  bf16* xb = P;                              // overlap: dead before K2 writes P
  bf16* WbT = (bf16*)((char*)P + 8 * MB);    // 6 MB, also dead before K2

  // K0: convert x, transpose+convert W
  k_cvt<<<dim3((TT * CC) / (256 * 8)), 256, 0, stream>>>(x, xb, TT * CC);
  k_wT<<<dim3(N3 / 64, CC / 64), 256, 0, stream>>>(W, WbT);
  // K1: QKV projection
  k_qkv<<<dim3(N3 / 128, TT / 128), 256, 0, stream>>>(xb, WbT, b, q, kk, vT);
  // K2: masked exp-scores + row sums
  hipMemsetAsync(l, 0, TT * sizeof(float), stream);
  k_scores<<<dim3(TT / 128, TT / 128), 256, 0, stream>>>(q, kk, P, l, npadd);
  // K3: split-K PV (+ zero the accumulator first; q/kk are dead now)
  hipMemsetAsync(yacc, 0, (size_t)TT * NFD * sizeof(float), stream);
  k_pvc<<<dim3(4, TT / 128, NFD / 128), 256, 0, stream>>>(P, vT, yacc, npadd);
  // K3b: normalize
  k_norm<<<dim3((TT * NFD) / (256 * 4)), 256, 0, stream>>>(yacc, l, y, npadd);
}

// Round 3
// 150.491 us; speedup vs baseline: 1.1604x; 1.0060x over previous
//
#include <hip/hip_runtime.h>
#include <hip/hip_bf16.h>
#include <stdint.h>
#include <stddef.h>

#define TT 4096
#define CC 1024
#define NFD 1024
#define N3 3072

typedef __bf16 bf16;
typedef __bf16 bf16x8 __attribute__((ext_vector_type(8)));
typedef __bf16 bf16x4 __attribute__((ext_vector_type(4)));
typedef float f32x4 __attribute__((ext_vector_type(4)));

typedef const __attribute__((address_space(1))) unsigned char gl_u8;
typedef __attribute__((address_space(3))) unsigned char lds_u8;

__device__ __forceinline__ void glds16(const void* g, void* l) {
  __builtin_amdgcn_global_load_lds((gl_u8*)g, (lds_u8*)l, 16, 0, 0);
}

// Stage a 128x32 bf16 tile (row-major, ld in elements) into linear LDS [128][32].
__device__ __forceinline__ void stage128x32(const bf16* __restrict__ src, int ld, bf16* lds, int tid) {
  const int lane = tid & 63;
  const int w = tid >> 6;
#pragma unroll
  for (int p = 0; p < 2; ++p) {
    const int lbyte = w * 2048 + p * 1024;              // wave-uniform LDS base (bytes)
    const int row = (lbyte >> 6) + (lane >> 2);         // this lane's 16B lands at row, k8
    const int kel = (lane & 3) << 3;
    glds16(src + row * ld + kel, (char*)lds + lbyte);
  }
}

// 128x128 output tile, 4 waves (2x2 of 64x64), BK=32, NT layout.
// Double-buffered: prefetch tile ks+1 while computing ks; single barrier per step
// (its implicit vmcnt(0) completes the prefetch AND gates the buffer swap).
// As/Bs must each hold 2*128*32 elements.
__device__ __forceinline__ void gemm_core(const bf16* __restrict__ A, const bf16* __restrict__ B,
                                          int lda, int ldb, int ksteps,
                                          bf16* As, bf16* Bs, int tid, f32x4 (&acc)[4][4]) {
  const int lane = tid & 63;
  const int w = tid >> 6;
  const int wm = (w >> 1) * 64;
  const int wn = (w & 1) * 64;
  const int lrow = lane & 15;
  const int lko = (lane >> 4) * 8;
  stage128x32(A, lda, As, tid);
  stage128x32(B, ldb, Bs, tid);
  __syncthreads();
  for (int ks = 0; ks < ksteps; ++ks) {
    const bf16* Ac = As + (ks & 1) * 4096;
    const bf16* Bc = Bs + (ks & 1) * 4096;
    if (ks + 1 < ksteps) {  // issue next-tile loads first; latency hides under MFMA below
      stage128x32(A + (ks + 1) * 32, lda, As + ((ks + 1) & 1) * 4096, tid);
      stage128x32(B + (ks + 1) * 32, ldb, Bs + ((ks + 1) & 1) * 4096, tid);
    }
    bf16x8 af[4], bfr[4];
#pragma unroll
    for (int i = 0; i < 4; ++i)
      af[i] = *(const bf16x8*)(Ac + (wm + i * 16 + lrow) * 32 + lko);
#pragma unroll
    for (int i = 0; i < 4; ++i)
      bfr[i] = *(const bf16x8*)(Bc + (wn + i * 16 + lrow) * 32 + lko);
#pragma unroll
    for (int mi = 0; mi < 4; ++mi)
#pragma unroll
      for (int ni = 0; ni < 4; ++ni)
        acc[mi][ni] = __builtin_amdgcn_mfma_f32_16x16x32_bf16(af[mi], bfr[ni], acc[mi][ni], 0, 0, 0);
    __syncthreads();  // vmcnt(0): prefetch landed; lgkm done; safe to overwrite other buf
  }
}

// ---- K0a: fp32 -> bf16 straight conversion (x) ----
__global__ void k_cvt(const float* __restrict__ src, bf16* __restrict__ dst, int n) {
  int idx = (blockIdx.x * blockDim.x + threadIdx.x) * 8;
  if (idx >= n) return;
  f32x4 a = *(const f32x4*)(src + idx);
  f32x4 b = *(const f32x4*)(src + idx + 4);
  bf16x8 o;
#pragma unroll
  for (int j = 0; j < 4; ++j) { o[j] = (bf16)a[j]; o[4 + j] = (bf16)b[j]; }
  *(bf16x8*)(dst + idx) = o;
}

// ---- K0b: W [C][3N] fp32 -> WbT [3N][C] bf16 (tiled transpose via LDS) ----
__global__ __launch_bounds__(256) void k_wT(const float* __restrict__ Wsrc, bf16* __restrict__ WbT) {
  __shared__ float Ls[64][68];
  const int n0 = blockIdx.x * 64;
  const int c0 = blockIdx.y * 64;
  const int tid = threadIdx.x;
#pragma unroll
  for (int qq = 0; qq < 4; ++qq) {
    int lin = qq * 1024 + tid * 4;
    int r = lin >> 6, cc = lin & 63;
    f32x4 v = *(const f32x4*)(Wsrc + (size_t)(c0 + r) * N3 + n0 + cc);
#pragma unroll
    for (int j = 0; j < 4; ++j) Ls[r][cc + j] = v[j];
  }
  __syncthreads();
#pragma unroll
  for (int qq = 0; qq < 4; ++qq) {
    int lin = qq * 1024 + tid * 4;
    int nr = lin >> 6, cc = lin & 63;
    bf16x4 o;
#pragma unroll
    for (int j = 0; j < 4; ++j) o[j] = (bf16)Ls[cc + j][nr];
    *(bf16x4*)(WbT + (size_t)(n0 + nr) * CC + c0 + cc) = o;
  }
}

// ---- K1: qkv = xb @ WbT^T + b ; writes q,k natural [t][c] and v transposed [d][t] ----
__global__ __launch_bounds__(256, 2) void k_qkv(const bf16* __restrict__ xb, const bf16* __restrict__ wbt,
                                                const float* __restrict__ bias,
                                                bf16* __restrict__ q, bf16* __restrict__ k,
                                                bf16* __restrict__ vT) {
  __shared__ bf16 As[2 * 128 * 32], Bs[2 * 128 * 32];
  const int tid = threadIdx.x;
  const int m0 = blockIdx.y * 128;
  const int n0 = blockIdx.x * 128;
  f32x4 acc[4][4];
#pragma unroll
  for (int i = 0; i < 4; ++i)
#pragma unroll
    for (int j = 0; j < 4; ++j) acc[i][j] = (f32x4){0.f, 0.f, 0.f, 0.f};

  gemm_core(xb + (size_t)m0 * CC, wbt + (size_t)n0 * CC, CC, CC, CC / 32, As, Bs, tid, acc);

  const int lane = tid & 63;
  const int w = tid >> 6;
  const int wm = (w >> 1) * 64, wn = (w & 1) * 64;
  const int seg = n0 >> 10;  // 0:q 1:k 2:v
#pragma unroll
  for (int mi = 0; mi < 4; ++mi) {
    const int tB = m0 + wm + mi * 16 + ((lane >> 4) << 2);
#pragma unroll
    for (int ni = 0; ni < 4; ++ni) {
      const int n = n0 + wn + ni * 16 + (lane & 15);
      const float bb = bias[n];
      f32x4 a = acc[mi][ni];
      if (seg == 2) {
        bf16x4 pv;
#pragma unroll
        for (int r = 0; r < 4; ++r) pv[r] = (bf16)(a[r] + bb);
        *(bf16x4*)(vT + (size_t)(n - 2048) * TT + tB) = pv;  // vT[d][t]
      } else {
        bf16* dst = (seg == 0) ? q : k;
        const int nl = n & 1023;
#pragma unroll
        for (int r = 0; r < 4; ++r) dst[(size_t)(tB + r) * NFD + nl] = (bf16)(a[r] + bb);
      }
    }
  }
}

// ---- K2: P' = exp(mask(q @ k^T / 32)) as bf16; row sums l via atomicAdd ----
__global__ __launch_bounds__(256, 2) void k_scores(const bf16* __restrict__ q, const bf16* __restrict__ kk,
                                                   bf16* __restrict__ P, float* __restrict__ l,
                                                   const int* __restrict__ npadd_p) {
  const int jt = blockIdx.x, it = blockIdx.y;
  const int np = *npadd_p;
  const int jt0 = np >> 7;
  if (jt > it || jt < jt0) return;  // fully-masked tile: never read by K3
  __shared__ bf16 As[2 * 128 * 32], Bs[2 * 128 * 32];
  const int tid = threadIdx.x;
  f32x4 acc[4][4];
#pragma unroll
  for (int i = 0; i < 4; ++i)
#pragma unroll
    for (int j = 0; j < 4; ++j) acc[i][j] = (f32x4){0.f, 0.f, 0.f, 0.f};

  gemm_core(q + (size_t)it * 128 * CC, kk + (size_t)jt * 128 * CC, CC, CC, CC / 32, As, Bs, tid, acc);

  const int lane = tid & 63;
  const int w = tid >> 6;
  const int wm = (w >> 1) * 64, wn = (w & 1) * 64;
  const float scale = 0.03125f;  // 1/sqrt(1024)
#pragma unroll
  for (int mi = 0; mi < 4; ++mi) {
    const int iB = it * 128 + wm + mi * 16 + ((lane >> 4) << 2);
    float rs[4] = {0.f, 0.f, 0.f, 0.f};
#pragma unroll
    for (int ni = 0; ni < 4; ++ni) {
      const int j = jt * 128 + wn + ni * 16 + (lane & 15);
      f32x4 a = acc[mi][ni];
#pragma unroll
      for (int r = 0; r < 4; ++r) {
        const int i = iB + r;
        float p = 0.f;
        if (j <= i && j >= np && i >= np) p = __expf(a[r] * scale);
        const bf16 pb = (bf16)p;
        P[(size_t)i * TT + j] = pb;
        rs[r] += (float)pb;  // sum the rounded value: weights then sum match exactly
      }
    }
#pragma unroll
    for (int r = 0; r < 4; ++r) {
      float v = rs[r];
      v += __shfl_xor(v, 1);
      v += __shfl_xor(v, 2);
      v += __shfl_xor(v, 4);
      v += __shfl_xor(v, 8);
      if ((lane & 15) == 0) atomicAdd(&l[iB + r], v);
    }
  }
}

// ---- K3a: split-K PV. chunk c covers j-tiles [8c, 8c+8); fp32 atomics into yacc ----
__global__ __launch_bounds__(256, 2) void k_pvc(const bf16* __restrict__ P, const bf16* __restrict__ vT,
                                                float* __restrict__ yacc,
                                                const int* __restrict__ npadd_p) {
  const int c = blockIdx.x;
  const int it = blockIdx.y;
  const int d0 = blockIdx.z * 128;
  const int np = *npadd_p;
  const int jt0 = np >> 7;
  int jlo = 8 * c; if (jlo < jt0) jlo = jt0;
  int jhi = 8 * c + 8; if (jhi > it + 1) jhi = it + 1;
  if (jlo >= jhi) return;  // empty / fully-masked chunk (also covers it < jt0)

  __shared__ bf16 As[2 * 128 * 32], Bs[2 * 128 * 32];
  const int tid = threadIdx.x;
  f32x4 acc[4][4];
#pragma unroll
  for (int i = 0; i < 4; ++i)
#pragma unroll
    for (int j = 0; j < 4; ++j) acc[i][j] = (f32x4){0.f, 0.f, 0.f, 0.f};

  gemm_core(P + (size_t)it * 128 * TT + (size_t)jlo * 128,
            vT + (size_t)d0 * TT + (size_t)jlo * 128,
            TT, TT, (jhi - jlo) * 4, As, Bs, tid, acc);

  const int lane = tid & 63;
  const int w = tid >> 6;
  const int wm = (w >> 1) * 64, wn = (w & 1) * 64;
  // sole-writer tile? (this chunk covers the row's entire valid j range)
  const bool full = (8 * c <= jt0) && (8 * c + 8 >= it + 1);
#pragma unroll
  for (int mi = 0; mi < 4; ++mi) {
    const int iB = it * 128 + wm + mi * 16 + ((lane >> 4) << 2);
#pragma unroll
    for (int ni = 0; ni < 4; ++ni) {
      const int d = d0 + wn + ni * 16 + (lane & 15);
      f32x4 a = acc[mi][ni];
#pragma unroll
      for (int r = 0; r < 4; ++r) {
        float* p = &yacc[(size_t)(iB + r) * NFD + d];
        if (full) *p = a[r];
        else atomicAdd(p, a[r]);
      }
    }
  }
}

// ---- K3b: y = yacc / l for i>=np else 0 ----
__global__ __launch_bounds__(256) void k_norm(const float* __restrict__ yacc, const float* __restrict__ l,
                                              float* __restrict__ y, const int* __restrict__ npadd_p) {
  const int idx = (blockIdx.x * 256 + threadIdx.x) * 4;
  const int i = idx >> 10;  // / NFD
  const int np = *npadd_p;
  f32x4 v = (f32x4){0.f, 0.f, 0.f, 0.f};
  if (i >= np) {
    f32x4 a = *(const f32x4*)(yacc + idx);
    const float inv = 1.0f / l[i];
#pragma unroll
    for (int j = 0; j < 4; ++j) v[j] = a[j] * inv;
  }
  *(f32x4*)(y + idx) = v;
}

extern "C" void kernel_launch(void* const* d_in, const int* in_sizes, int n_in,
                              void* d_out, int out_size, void* d_ws, size_t ws_size,
                              hipStream_t stream) {
  const float* x = (const float*)d_in[0];
  const float* W = (const float*)d_in[1];
  const float* b = (const float*)d_in[2];
  const int* npadd = (const int*)d_in[3];
  float* y = (float*)d_out;

  char* ws = (char*)d_ws;
  const size_t MB = 1u << 20;
  bf16* q  = (bf16*)(ws + 0 * MB);          // 8 MB  [T][C]   (dead after k_scores)
  bf16* kk = (bf16*)(ws + 8 * MB);          // 8 MB  [T][C]   (dead after k_scores)
  float* yacc = (float*)(ws + 0 * MB);      // 16 MB [T][D] fp32, overlays q+kk
  bf16* vT = (bf16*)(ws + 16 * MB);         // 8 MB  [D][T]
  float* l = (float*)(ws + 24 * MB);        // 16 KB
  bf16* P  = (bf16*)(ws + 24 * MB + 65536); // 32 MB [T][T]
  bf16* xb = P;                              // overlap: dead before K2 writes P
  bf16* WbT = (bf16*)((char*)P + 8 * MB);    // 6 MB, also dead before K2

  // K0: convert x, transpose+convert W
  k_cvt<<<dim3((TT * CC) / (256 * 8)), 256, 0, stream>>>(x, xb, TT * CC);
  k_wT<<<dim3(N3 / 64, CC / 64), 256, 0, stream>>>(W, WbT);
  // K1: QKV projection
  k_qkv<<<dim3(N3 / 128, TT / 128), 256, 0, stream>>>(xb, WbT, b, q, kk, vT);
  // K2: masked exp-scores + row sums
  hipMemsetAsync(l, 0, TT * sizeof(float), stream);
  k_scores<<<dim3(TT / 128, TT / 128), 256, 0, stream>>>(q, kk, P, l, npadd);
  // K3: split-K PV (+ zero the accumulator first; q/kk are dead now)
  hipMemsetAsync(yacc, 0, (size_t)TT * NFD * sizeof(float), stream);
  k_pvc<<<dim3(4, TT / 128, NFD / 128), 256, 0, stream>>>(P, vT, yacc, npadd);
  // K3b: normalize
  k_norm<<<dim3((TT * NFD) / (256 * 4)), 256, 0, stream>>>(yacc, l, y, npadd);
}